// Round 9
// baseline (516.151 us; speedup 1.0000x reference)
//
#include <hip/hip_runtime.h>
#include <hip/hip_fp16.h>

// Problem constants (from reference)
#define Nn 200000
#define Ee 6400000
#define EP 6600000            // Ee + Nn self loops
#define Hh 9
#define Ll 4
#define Gg 2000
#define Cc 2
#define JK 36                 // Ll * Hh
#define NCB ((Nn + 1023) >> 10) // 196 coarse buckets (1024 nodes each)
#define EPB 8192              // edges per phase-A block
#define NBLKA ((EP + EPB - 1) / EPB) // 806
#define NB ((Nn + 255) / 256) // 782
#define NPB 32                // nodes per k_node_agg block (oct per node)
#define NAB (Nn / NPB)        // 6250 blocks
#define CAP 3072              // staged csr entries per block (12 KB)
#define CAPB 36864            // kB_csr staged entries (144 KB)
#define HTS (NCB + 1)         // histT row stride

union H2F { __half2 h; float f; };

// ========= CSR build: block-major multisplit + per-bucket LDS sort =========
// R9: single csr again (R8's half-split was a measured null). kA uses
// PER-WAVE histograms and cursors — R8 counters showed kA is LDS-atomic
// serialization bound (11% HBM, 7% VALU, 2.6M conflict cycles); per-wave
// copies remove all cross-wave same-address contention.

// Phase A: per-block LDS multisplit, drained BLOCK-MAJOR.
// Payload: src (18b) | dst low 10 bits << 18.
__global__ __launch_bounds__(256) void kA_scatter(
    const int* __restrict__ src, const int* __restrict__ dst,
    int* __restrict__ ctot, int* __restrict__ histT,
    unsigned* __restrict__ bucketed)
{
    __shared__ unsigned pbuf[EPB];        // 32 KB
    __shared__ int lh[4 * NCB];           // per-wave hist -> cursors (3.1 KB)
    __shared__ int s[256];
    int t = threadIdx.x;
    const int w = t >> 6;                 // wave id (0..3)
    for (int j = t; j < 4 * NCB; j += 256) lh[j] = 0;
    __syncthreads();
    const int base = blockIdx.x * EPB;
    const int nseg = min(EPB, EP - base);
    // pass 1: per-wave coarse histogram (dst only). Thread t's edge set
    // (j = t mod 256) is fixed, so wave ownership matches pass 2.
    for (int j = t; j < nseg; j += 256) {
        int e = base + j;
        int d = (e < Ee) ? dst[e] : (e - Ee);
        atomicAdd(&lh[w * NCB + (d >> 10)], 1);
    }
    __syncthreads();
    // merge 4 wave histograms; scan bin totals; write per-wave cursor starts
    int c0 = 0, c1 = 0, c2 = 0, c3 = 0, tot = 0;
    if (t < NCB) {
        c0 = lh[t]; c1 = lh[NCB + t]; c2 = lh[2 * NCB + t]; c3 = lh[3 * NCB + t];
        tot = c0 + c1 + c2 + c3;
    }
    s[t] = tot; __syncthreads();
    for (int off = 1; off < 256; off <<= 1) {
        int u = (t >= off) ? s[t - off] : 0;
        __syncthreads();
        s[t] += u;
        __syncthreads();
    }
    int* hrow = histT + (size_t)blockIdx.x * HTS;
    if (t < NCB) {
        int ex = s[t] - tot;               // exclusive over bins
        lh[t] = ex;                        // wave-0 cursor
        lh[NCB + t] = ex + c0;             // wave-1 cursor
        lh[2 * NCB + t] = ex + c0 + c1;    // wave-2 cursor
        lh[3 * NCB + t] = ex + c0 + c1 + c2;
        hrow[t] = ex;                      // run start for kB
        if (tot) atomicAdd(&ctot[t], tot);
    }
    if (t == 0) hrow[NCB] = nseg;
    __syncthreads();
    // pass 2: scatter into LDS using per-wave cursors (no cross-wave atomics)
    for (int j = t; j < nseg; j += 256) {
        int e = base + j;
        int sv, d;
        if (e < Ee) { sv = src[e]; d = dst[e]; } else { sv = e - Ee; d = sv; }
        int pos = atomicAdd(&lh[w * NCB + (d >> 10)], 1);
        pbuf[pos] = (unsigned)sv | ((unsigned)(d & 1023) << 18);
    }
    __syncthreads();
    // pass 3: straight coalesced drain, block-major
    for (int j = t; j < nseg; j += 256)
        bucketed[base + j] = pbuf[j];
}

// Scan coarse totals -> cbase.
__global__ __launch_bounds__(256) void k_scan(
    const int* __restrict__ ctot, int* __restrict__ cbase,
    int* __restrict__ row_ptr)
{
    __shared__ int s[256];
    int t = threadIdx.x;
    int v = (t < NCB) ? ctot[t] : 0;
    s[t] = v; __syncthreads();
    for (int off = 1; off < 256; off <<= 1) {
        int u = (t >= off) ? s[t - off] : 0;
        __syncthreads();
        s[t] += u;
        __syncthreads();
    }
    if (t < NCB) cbase[t] = s[t] - v;
    if (t == 0) { cbase[NCB] = EP; row_ptr[Nn] = EP; }
}

// Phase B: ONE 1024-thread block per coarse bucket. 1024 fine bins,
// barrier-free wave-shfl scan, run bounds preloaded to LDS, 4-way run
// pipelining (4 outstanding gathers/wave).
__global__ __launch_bounds__(1024) void kB_csr(
    const unsigned* __restrict__ bucketed, const int* __restrict__ histT,
    const int* __restrict__ cbase, int* __restrict__ row_ptr,
    int* __restrict__ csr_src)
{
    __shared__ int2 hb[NBLKA];            // 6.45 KB run bounds
    __shared__ int bh[1024];              // 4 KB: hist -> cursors
    __shared__ unsigned pbuf[CAPB];       // 144 KB (154.5 KB total)
    __shared__ int wsum[16];
    const int k = blockIdx.x;
    const int t = threadIdx.x;
    const int w = t >> 6, lane = t & 63;  // 16 waves
    bh[t] = 0;
    for (int j = t; j < NBLKA; j += 1024) {
        const int* hrow = histT + (size_t)j * HTS + k;
        hb[j] = make_int2(hrow[0], hrow[1]);
    }
    __syncthreads();
    // pass 1: 1024-bin histogram, 4 runs in flight per wave
    for (int b = w; b < NBLKA; b += 16 * 4) {
        int2 es[4]; unsigned ps[4];
#pragma unroll
        for (int u = 0; u < 4; ++u) {
            int bb = b + 16 * u;
            int2 e = (bb < NBLKA) ? hb[bb] : make_int2(0, 0);
            es[u] = e;
            int j = e.x + lane;
            ps[u] = (j < e.y)
                ? __builtin_nontemporal_load(bucketed + (size_t)bb * EPB + j)
                : 0u;
        }
#pragma unroll
        for (int u = 0; u < 4; ++u) {
            int bb = b + 16 * u;
            if (bb >= NBLKA) break;
            int j = es[u].x + lane;
            if (j < es[u].y) atomicAdd(&bh[(ps[u] >> 18) & 1023], 1);
            for (j += 64; j < es[u].y; j += 64) {   // rare (run > 64)
                unsigned p = __builtin_nontemporal_load(
                    bucketed + (size_t)bb * EPB + j);
                atomicAdd(&bh[(p >> 18) & 1023], 1);
            }
        }
    }
    __syncthreads();
    // exclusive scan of 1024 bins: wave shfl scan + cross-wave bases
    int v = bh[t];
    int incl = v;
#pragma unroll
    for (int off = 1; off < 64; off <<= 1) {
        int u = __shfl_up(incl, off);
        if (lane >= off) incl += u;
    }
    if (lane == 63) wsum[w] = incl;
    __syncthreads();
    if (t == 0) {
        int acc = 0;
#pragma unroll
        for (int i2 = 0; i2 < 16; ++i2) { int x = wsum[i2]; wsum[i2] = acc; acc += x; }
    }
    __syncthreads();
    int excl = wsum[w] + incl - v;
    const int base_k = cbase[k];
    const int nseg_b = cbase[k + 1] - base_k;
    const int node = (k << 10) + t;
    if (node < Nn) row_ptr[node] = base_k + excl;
    bh[t] = excl;                         // pbuf-relative cursor
    __syncthreads();
    const bool fit = (nseg_b <= CAPB);
    if (fit) {
        // pass 2: scatter into LDS pbuf, 4 runs in flight per wave
        for (int b = w; b < NBLKA; b += 16 * 4) {
            int2 es[4]; unsigned ps[4];
#pragma unroll
            for (int u = 0; u < 4; ++u) {
                int bb = b + 16 * u;
                int2 e = (bb < NBLKA) ? hb[bb] : make_int2(0, 0);
                es[u] = e;
                int j = e.x + lane;
                ps[u] = (j < e.y)
                    ? __builtin_nontemporal_load(bucketed + (size_t)bb * EPB + j)
                    : 0u;
            }
#pragma unroll
            for (int u = 0; u < 4; ++u) {
                int bb = b + 16 * u;
                if (bb >= NBLKA) break;
                int j = es[u].x + lane;
                if (j < es[u].y) {
                    unsigned p = ps[u];
                    int pos = atomicAdd(&bh[(p >> 18) & 1023], 1);
                    pbuf[pos] = p & 0x3FFFFu;
                }
                for (j += 64; j < es[u].y; j += 64) {   // rare (run > 64)
                    unsigned p = __builtin_nontemporal_load(
                        bucketed + (size_t)bb * EPB + j);
                    int pos = atomicAdd(&bh[(p >> 18) & 1023], 1);
                    pbuf[pos] = p & 0x3FFFFu;
                }
            }
        }
        __syncthreads();
        // fully-coalesced drain
        for (int j = t; j < nseg_b; j += 1024)
            csr_src[base_k + j] = (int)pbuf[j];
    } else {
        // fallback: direct global scatter (statistically never)
        for (int b = w; b < NBLKA; b += 16) {
            int2 e = hb[b];
            int rb = b * EPB;
            for (int j = e.x + lane; j < e.y; j += 64) {
                unsigned p = bucketed[rb + j];
                int pos = base_k + atomicAdd(&bh[(p >> 18) & 1023], 1);
                csr_src[pos] = (int)(p & 0x3FFFFu);
            }
        }
    }
}

// ============ per-layer kernels ============

// ONE 32B packed record per node:
//   P[i] @ i*32: [0..15] h0..h7 as 4x half2, [16..19] h8 fp32,
//                [20..23] alpha_d fp32, [24..31] pad.
// Per edge both loads hit the SAME 64B line -> one L2 request.
// jk is LAYER-MAJOR [L][Nn][9]: contiguous 36B writes per node.
__global__ __launch_bounds__(256) void k_transform(
    const float* __restrict__ xin, int xstride,
    const float* __restrict__ Wl,
    const float* __restrict__ adst,
    char* __restrict__ P)
{
    int i = blockIdx.x * blockDim.x + threadIdx.x;
    if (i >= Nn) return;
    const float* xp = xin + (size_t)i * xstride;
    float xi[Hh];
#pragma unroll
    for (int k = 0; k < Hh; ++k) xi[k] = xp[k];
    float hv[Hh];
#pragma unroll
    for (int j = 0; j < Hh; ++j) {
        float s = 0.f;
#pragma unroll
        for (int k = 0; k < Hh; ++k) s += xi[k] * Wl[k * Hh + j];
        hv[j] = s;
    }
    float ad = 0.f;
#pragma unroll
    for (int j = 0; j < Hh; ++j) ad += hv[j] * adst[j];
    H2F u01, u23, u45, u67;
    u01.h = __floats2half2_rn(hv[0], hv[1]);
    u23.h = __floats2half2_rn(hv[2], hv[3]);
    u45.h = __floats2half2_rn(hv[4], hv[5]);
    u67.h = __floats2half2_rn(hv[6], hv[7]);
    char* rp = P + ((size_t)i << 5);
    *(float4*)rp        = make_float4(u01.f, u23.f, u45.f, u67.f);
    *(float2*)(rp + 16) = make_float2(hv[8], ad);
}

// Per-edge math. x8 is fp32 in the record.
#define AGG_EDGE(F, X8)                                                     \
    {                                                                       \
        H2F u; float2 p;                                                    \
        u.f = (F).x; p = __half22float2(u.h); float x0 = p.x, x1 = p.y;     \
        u.f = (F).y; p = __half22float2(u.h); float x2 = p.x, x3 = p.y;     \
        u.f = (F).z; p = __half22float2(u.h); float x4 = p.x, x5 = p.y;     \
        u.f = (F).w; p = __half22float2(u.h); float x6 = p.x, x7 = p.y;     \
        float x8 = (X8);                                                    \
        float as = x0*s0 + x1*s1 + x2*s2 + x3*s3 + x4*s4                    \
                 + x5*s5 + x6*s6 + x7*s7 + x8*s8;                           \
        float lg = as + c;                                                  \
        lg = lg > 0.f ? lg : 0.2f * lg;                                     \
        float wgt = __expf(lg);                                             \
        a0 += wgt*x0; a1 += wgt*x1; a2 += wgt*x2; a3 += wgt*x3;             \
        a4 += wgt*x4; a5 += wgt*x5; a6 += wgt*x6; a7 += wgt*x7;             \
        a8 += wgt*x8; den += wgt;                                           \
    }

// Oct-per-node gather, LDS-staged CSR, two 2-deep pipelines (4 in flight).
// Single-pass softmax: |logits| << 88 so exp never overflows; ratio exact.
__global__ __launch_bounds__(256) void k_node_agg(
    const int* __restrict__ rp, const int* __restrict__ csr,
    const char* __restrict__ P, const float* __restrict__ asrc,
    const float* __restrict__ biasl,
    float* __restrict__ jk, int l)
{
    __shared__ int scsr[CAP];
    __shared__ int srp[NPB + 1];
    const int nbase = blockIdx.x * NPB;
    const int t = threadIdx.x;
    if (t <= NPB) srp[t] = rp[nbase + t];   // nbase+NPB <= Nn; rp[Nn] = EP
    __syncthreads();
    const int beg_blk = srp[0];
    const int nseg = srp[NPB] - beg_blk;
    const bool use_lds = (nseg <= CAP);
    if (use_lds)
        for (int j = t; j < nseg; j += 256)
            scsr[j] = __builtin_nontemporal_load(csr + beg_blk + j);
    __syncthreads();

    const float s0 = asrc[0], s1 = asrc[1], s2 = asrc[2], s3 = asrc[3],
                s4 = asrc[4], s5 = asrc[5], s6 = asrc[6], s7 = asrc[7],
                s8 = asrc[8];

    const int ni = t >> 3;          // node within block
    const int q  = t & 7;           // lane within oct
    const int i  = nbase + ni;
    const float c = *(const float*)(P + ((size_t)i << 5) + 20); // own alpha_d
    float a0=0,a1=0,a2=0,a3=0,a4=0,a5=0,a6=0,a7=0,a8=0,den=0;
    if (use_lds) {
        const int iend = srp[ni + 1] - beg_blk;
        int i0 = srp[ni] - beg_blk + q;
        int i1 = i0 + 8;
        int sv0 = (i0 < iend) ? scsr[i0] : 0;
        int sv1 = (i1 < iend) ? scsr[i1] : 0;
        const char* r0 = P + ((size_t)sv0 << 5);
        const char* r1 = P + ((size_t)sv1 << 5);
        float4 F0 = *(const float4*)r0; float e0 = *(const float*)(r0 + 16);
        float4 F1 = *(const float4*)r1; float e1 = *(const float*)(r1 + 16);
        while (i0 < iend) {
            int n0 = i0 + 16, n1 = i1 + 16;
            int sn0 = (n0 < iend) ? scsr[n0] : 0;
            int sn1 = (n1 < iend) ? scsr[n1] : 0;
            const char* rn0 = P + ((size_t)sn0 << 5);
            const char* rn1 = P + ((size_t)sn1 << 5);
            float4 Fn0 = *(const float4*)rn0;
            float en0 = *(const float*)(rn0 + 16);
            float4 Fn1 = *(const float4*)rn1;
            float en1 = *(const float*)(rn1 + 16);
            AGG_EDGE(F0, e0);
            if (i1 < iend) AGG_EDGE(F1, e1);
            F0 = Fn0; e0 = en0; F1 = Fn1; e1 = en1;
            i0 = n0; i1 = n1;
        }
    } else {
        for (int e = srp[ni] + q; e < srp[ni + 1]; e += 8) {
            int s = csr[e];
            const char* r0 = P + ((size_t)s << 5);
            float4 F = *(const float4*)r0;
            float e8 = *(const float*)(r0 + 16);
            AGG_EDGE(F, e8);
        }
    }
#pragma unroll
    for (int m = 1; m <= 4; m <<= 1) {
        a0 += __shfl_xor(a0, m); a1 += __shfl_xor(a1, m);
        a2 += __shfl_xor(a2, m); a3 += __shfl_xor(a3, m);
        a4 += __shfl_xor(a4, m); a5 += __shfl_xor(a5, m);
        a6 += __shfl_xor(a6, m); a7 += __shfl_xor(a7, m);
        a8 += __shfl_xor(a8, m); den += __shfl_xor(den, m);
    }
    if (q == 0) {
        float inv = 1.f / den;          // den >= 1 (self-loop term)
        float* jp = jk + (size_t)l * Nn * Hh + (size_t)i * Hh;
        jp[0] = fmaxf(a0*inv + biasl[0], 0.f);
        jp[1] = fmaxf(a1*inv + biasl[1], 0.f);
        jp[2] = fmaxf(a2*inv + biasl[2], 0.f);
        jp[3] = fmaxf(a3*inv + biasl[3], 0.f);
        jp[4] = fmaxf(a4*inv + biasl[4], 0.f);
        jp[5] = fmaxf(a5*inv + biasl[5], 0.f);
        jp[6] = fmaxf(a6*inv + biasl[6], 0.f);
        jp[7] = fmaxf(a7*inv + biasl[7], 0.f);
        jp[8] = fmaxf(a8*inv + biasl[8], 0.f);
    }
}

// ============ pool + fc ============

__global__ __launch_bounds__(256) void k_graph_ptr(
    const int* __restrict__ batch, int* __restrict__ gp)
{
    int i = blockIdx.x * 256 + threadIdx.x;
    if (i >= Nn) return;
    int b = batch[i];
    if (i == 0) {
        for (int g = 0; g <= b; ++g) gp[g] = 0;
    } else {
        int pb = batch[i - 1];
        for (int g = pb + 1; g <= b; ++g) gp[g] = i;
    }
    if (i == Nn - 1) {
        for (int g = b + 1; g <= Gg; ++g) gp[g] = Nn;
    }
}

// Segmented max over layer-major jk [L][Nn][9]; concat order col = l*9+c.
__global__ __launch_bounds__(256) void k_pool_seg(
    const float* __restrict__ jk, const int* __restrict__ gp,
    float* __restrict__ pooled)
{
    int t = blockIdx.x * 256 + threadIdx.x;
    if (t >= Gg * JK) return;
    int g = t / JK, col = t - g * JK;
    int lc = col / Hh, cc = col - lc * Hh;
    const float* bp = jk + (size_t)lc * Nn * Hh + cc;
    int beg = gp[g], end = gp[g + 1];
    float m = 0.f;
    for (int i = beg; i < end; ++i)
        m = fmaxf(m, bp[(size_t)i * Hh]);
    pooled[t] = m;
}

__global__ __launch_bounds__(256) void k_fc(
    const float* __restrict__ pooled, const float* __restrict__ fcw,
    const float* __restrict__ fcb, float* __restrict__ out)
{
    int t = blockIdx.x * blockDim.x + threadIdx.x;
    if (t >= Gg * Cc) return;
    int g = t / Cc, c = t - g * Cc;
    float s = fcb[c];
    const float* pp = pooled + (size_t)g * JK;
#pragma unroll
    for (int j = 0; j < JK; ++j) s += pp[j] * fcw[j * Cc + c];
    out[t] = s;
}

extern "C" void kernel_launch(void* const* d_in, const int* in_sizes, int n_in,
                              void* d_out, int out_size, void* d_ws, size_t ws_size,
                              hipStream_t stream) {
    const float* x      = (const float*)d_in[0];   // [N,9]
    const int*   ei     = (const int*)d_in[1];     // [2,E]
    const int*   batch  = (const int*)d_in[2];     // [N] sorted
    const float* W      = (const float*)d_in[3];   // [L,9,9]
    const float* a_src  = (const float*)d_in[4];   // [L,9]
    const float* a_dst  = (const float*)d_in[5];   // [L,9]
    const float* bias   = (const float*)d_in[6];   // [L,9]
    const float* fc_w   = (const float*)d_in[7];   // [36,2]
    const float* fc_b   = (const float*)d_in[8];   // [2]
    float* out = (float*)d_out;

    // Workspace (~64 MB). histT aliases P, bucketed aliases jk — both dead
    // before P/jk are first written (same-stream ordering).
    char* P          = (char*)d_ws;                       // Nn*32B (6.4MB)
    float* jk        = (float*)(P + ((size_t)Nn << 5));   // Nn*JK (28.8MB)
    float* pooled    = jk + (size_t)Nn * JK;              // Gg*JK
    int* row_ptr     = (int*)(pooled + (size_t)Gg * JK);  // Nn+1
    int* gp          = row_ptr + Nn + 1;                  // Gg+1
    int* ctot        = gp + Gg + 1;                       // NCB
    int* cbase       = ctot + NCB;                        // NCB+1
    int* csr_src     = cbase + NCB + 1;                   // EP (26.4MB)
    int* histT       = (int*)P;                           // aliases P
    unsigned* bucketed = (unsigned*)jk;                   // aliases jk

    const int* srcp = ei;
    const int* dstp = ei + Ee;

    // CSR build (edge structure is layer-invariant)
    hipMemsetAsync(ctot, 0, NCB * sizeof(int), stream);
    kA_scatter<<<NBLKA, 256, 0, stream>>>(srcp, dstp, ctot, histT, bucketed);
    k_scan    <<<1, 256, 0, stream>>>(ctot, cbase, row_ptr);
    kB_csr    <<<NCB, 1024, 0, stream>>>(bucketed, histT, cbase, row_ptr,
                                         csr_src);

    for (int l = 0; l < Ll; ++l) {
        const float* xin = (l == 0) ? x : (jk + (size_t)(l - 1) * Nn * Hh);
        k_transform<<<NB, 256, 0, stream>>>(xin, Hh, W + l * Hh * Hh,
                                            a_dst + l * Hh, P);
        k_node_agg<<<NAB, 256, 0, stream>>>(row_ptr, csr_src, P,
                                            a_src + l * Hh, bias + l * Hh,
                                            jk, l);
    }
    k_graph_ptr<<<NB, 256, 0, stream>>>(batch, gp);
    k_pool_seg<<<(Gg * JK + 255) / 256, 256, 0, stream>>>(jk, gp, pooled);
    k_fc<<<(Gg * Cc + 255) / 256, 256, 0, stream>>>(pooled, fc_w, fc_b, out);
}

// Round 10
// 493.688 us; speedup vs baseline: 1.0455x; 1.0455x over previous
//
#include <hip/hip_runtime.h>
#include <hip/hip_fp16.h>

// Problem constants (from reference)
#define Nn 200000
#define Ee 6400000
#define EP 6600000            // Ee + Nn self loops
#define Hh 9
#define Ll 4
#define Gg 2000
#define Cc 2
#define JK 36                 // Ll * Hh
#define NCB ((Nn + 1023) >> 10) // 196 coarse buckets (1024 nodes each)
#define EPB 8192              // edges per phase-A block
#define NBLKA ((EP + EPB - 1) / EPB) // 806
#define NB ((Nn + 255) / 256) // 782
#define NPB 32                // nodes per k_node_agg block (oct per node)
#define NAB (Nn / NPB)        // 6250 blocks
#define CAP 3072              // staged csr entries per block (12 KB)
#define CAPB 36864            // kB_csr staged entries (144 KB)
#define HTS (NCB + 1)         // histT row stride

union H2F { __half2 h; float f; };

// ========= CSR build: block-major multisplit + per-bucket LDS sort =========
// R10: CSR pipeline unchanged from R9 (kA/kB each plateaued at ~65 µs across
// 3 structural attempts — latency/LDS-atomic floor for this formulation).

// Phase A: per-block LDS multisplit, drained BLOCK-MAJOR.
// Payload: src (18b) | dst low 10 bits << 18.
__global__ __launch_bounds__(256) void kA_scatter(
    const int* __restrict__ src, const int* __restrict__ dst,
    int* __restrict__ ctot, int* __restrict__ histT,
    unsigned* __restrict__ bucketed)
{
    __shared__ unsigned pbuf[EPB];        // 32 KB
    __shared__ int lh[4 * NCB];           // per-wave hist -> cursors (3.1 KB)
    __shared__ int s[256];
    int t = threadIdx.x;
    const int w = t >> 6;                 // wave id (0..3)
    for (int j = t; j < 4 * NCB; j += 256) lh[j] = 0;
    __syncthreads();
    const int base = blockIdx.x * EPB;
    const int nseg = min(EPB, EP - base);
    // pass 1: per-wave coarse histogram (dst only)
    for (int j = t; j < nseg; j += 256) {
        int e = base + j;
        int d = (e < Ee) ? dst[e] : (e - Ee);
        atomicAdd(&lh[w * NCB + (d >> 10)], 1);
    }
    __syncthreads();
    // merge 4 wave histograms; scan bin totals; per-wave cursor starts
    int c0 = 0, c1 = 0, c2 = 0, c3 = 0, tot = 0;
    if (t < NCB) {
        c0 = lh[t]; c1 = lh[NCB + t]; c2 = lh[2 * NCB + t]; c3 = lh[3 * NCB + t];
        tot = c0 + c1 + c2 + c3;
    }
    s[t] = tot; __syncthreads();
    for (int off = 1; off < 256; off <<= 1) {
        int u = (t >= off) ? s[t - off] : 0;
        __syncthreads();
        s[t] += u;
        __syncthreads();
    }
    int* hrow = histT + (size_t)blockIdx.x * HTS;
    if (t < NCB) {
        int ex = s[t] - tot;
        lh[t] = ex;
        lh[NCB + t] = ex + c0;
        lh[2 * NCB + t] = ex + c0 + c1;
        lh[3 * NCB + t] = ex + c0 + c1 + c2;
        hrow[t] = ex;
        if (tot) atomicAdd(&ctot[t], tot);
    }
    if (t == 0) hrow[NCB] = nseg;
    __syncthreads();
    // pass 2: scatter into LDS using per-wave cursors
    for (int j = t; j < nseg; j += 256) {
        int e = base + j;
        int sv, d;
        if (e < Ee) { sv = src[e]; d = dst[e]; } else { sv = e - Ee; d = sv; }
        int pos = atomicAdd(&lh[w * NCB + (d >> 10)], 1);
        pbuf[pos] = (unsigned)sv | ((unsigned)(d & 1023) << 18);
    }
    __syncthreads();
    // pass 3: straight coalesced drain, block-major
    for (int j = t; j < nseg; j += 256)
        bucketed[base + j] = pbuf[j];
}

// Scan coarse totals -> cbase.
__global__ __launch_bounds__(256) void k_scan(
    const int* __restrict__ ctot, int* __restrict__ cbase,
    int* __restrict__ row_ptr)
{
    __shared__ int s[256];
    int t = threadIdx.x;
    int v = (t < NCB) ? ctot[t] : 0;
    s[t] = v; __syncthreads();
    for (int off = 1; off < 256; off <<= 1) {
        int u = (t >= off) ? s[t - off] : 0;
        __syncthreads();
        s[t] += u;
        __syncthreads();
    }
    if (t < NCB) cbase[t] = s[t] - v;
    if (t == 0) { cbase[NCB] = EP; row_ptr[Nn] = EP; }
}

// Phase B: ONE 1024-thread block per coarse bucket. 1024 fine bins,
// barrier-free wave-shfl scan, run bounds preloaded to LDS, 4-way run
// pipelining (4 outstanding gathers/wave).
__global__ __launch_bounds__(1024) void kB_csr(
    const unsigned* __restrict__ bucketed, const int* __restrict__ histT,
    const int* __restrict__ cbase, int* __restrict__ row_ptr,
    int* __restrict__ csr_src)
{
    __shared__ int2 hb[NBLKA];            // 6.45 KB run bounds
    __shared__ int bh[1024];              // 4 KB: hist -> cursors
    __shared__ unsigned pbuf[CAPB];       // 144 KB
    __shared__ int wsum[16];
    const int k = blockIdx.x;
    const int t = threadIdx.x;
    const int w = t >> 6, lane = t & 63;  // 16 waves
    bh[t] = 0;
    for (int j = t; j < NBLKA; j += 1024) {
        const int* hrow = histT + (size_t)j * HTS + k;
        hb[j] = make_int2(hrow[0], hrow[1]);
    }
    __syncthreads();
    // pass 1: 1024-bin histogram, 4 runs in flight per wave
    for (int b = w; b < NBLKA; b += 16 * 4) {
        int2 es[4]; unsigned ps[4];
#pragma unroll
        for (int u = 0; u < 4; ++u) {
            int bb = b + 16 * u;
            int2 e = (bb < NBLKA) ? hb[bb] : make_int2(0, 0);
            es[u] = e;
            int j = e.x + lane;
            ps[u] = (j < e.y)
                ? __builtin_nontemporal_load(bucketed + (size_t)bb * EPB + j)
                : 0u;
        }
#pragma unroll
        for (int u = 0; u < 4; ++u) {
            int bb = b + 16 * u;
            if (bb >= NBLKA) break;
            int j = es[u].x + lane;
            if (j < es[u].y) atomicAdd(&bh[(ps[u] >> 18) & 1023], 1);
            for (j += 64; j < es[u].y; j += 64) {
                unsigned p = __builtin_nontemporal_load(
                    bucketed + (size_t)bb * EPB + j);
                atomicAdd(&bh[(p >> 18) & 1023], 1);
            }
        }
    }
    __syncthreads();
    // exclusive scan of 1024 bins: wave shfl scan + cross-wave bases
    int v = bh[t];
    int incl = v;
#pragma unroll
    for (int off = 1; off < 64; off <<= 1) {
        int u = __shfl_up(incl, off);
        if (lane >= off) incl += u;
    }
    if (lane == 63) wsum[w] = incl;
    __syncthreads();
    if (t == 0) {
        int acc = 0;
#pragma unroll
        for (int i2 = 0; i2 < 16; ++i2) { int x = wsum[i2]; wsum[i2] = acc; acc += x; }
    }
    __syncthreads();
    int excl = wsum[w] + incl - v;
    const int base_k = cbase[k];
    const int nseg_b = cbase[k + 1] - base_k;
    const int node = (k << 10) + t;
    if (node < Nn) row_ptr[node] = base_k + excl;
    bh[t] = excl;                         // pbuf-relative cursor
    __syncthreads();
    const bool fit = (nseg_b <= CAPB);
    if (fit) {
        // pass 2: scatter into LDS pbuf, 4 runs in flight per wave
        for (int b = w; b < NBLKA; b += 16 * 4) {
            int2 es[4]; unsigned ps[4];
#pragma unroll
            for (int u = 0; u < 4; ++u) {
                int bb = b + 16 * u;
                int2 e = (bb < NBLKA) ? hb[bb] : make_int2(0, 0);
                es[u] = e;
                int j = e.x + lane;
                ps[u] = (j < e.y)
                    ? __builtin_nontemporal_load(bucketed + (size_t)bb * EPB + j)
                    : 0u;
            }
#pragma unroll
            for (int u = 0; u < 4; ++u) {
                int bb = b + 16 * u;
                if (bb >= NBLKA) break;
                int j = es[u].x + lane;
                if (j < es[u].y) {
                    unsigned p = ps[u];
                    int pos = atomicAdd(&bh[(p >> 18) & 1023], 1);
                    pbuf[pos] = p & 0x3FFFFu;
                }
                for (j += 64; j < es[u].y; j += 64) {
                    unsigned p = __builtin_nontemporal_load(
                        bucketed + (size_t)bb * EPB + j);
                    int pos = atomicAdd(&bh[(p >> 18) & 1023], 1);
                    pbuf[pos] = p & 0x3FFFFu;
                }
            }
        }
        __syncthreads();
        // fully-coalesced drain
        for (int j = t; j < nseg_b; j += 1024)
            csr_src[base_k + j] = (int)pbuf[j];
    } else {
        // fallback: direct global scatter (statistically never)
        for (int b = w; b < NBLKA; b += 16) {
            int2 e = hb[b];
            int rb = b * EPB;
            for (int j = e.x + lane; j < e.y; j += 64) {
                unsigned p = bucketed[rb + j];
                int pos = base_k + atomicAdd(&bh[(p >> 18) & 1023], 1);
                csr_src[pos] = (int)(p & 0x3FFFFu);
            }
        }
    }
}

// ============ per-layer kernels ============

// ONE 32B packed record per node:
//   P[i] @ i*32: [0..15] h0..h7 as 4x half2, [16..19] h8 fp32,
//                [20..23] alpha_d fp32, [24..31] pad.
// R10: k_transform runs ONCE (layer 0, from x). Layers 1..3 records are
// produced by the PREVIOUS agg's epilogue (fusion kills 3 dispatches + 3x
// 13.6MB of jk re-read / P re-write). P is ping-pong double-buffered since
// agg reads neighbors' records while producing next-layer records.
__global__ __launch_bounds__(256) void k_transform(
    const float* __restrict__ xin, int xstride,
    const float* __restrict__ Wl,
    const float* __restrict__ adst,
    char* __restrict__ P)
{
    int i = blockIdx.x * blockDim.x + threadIdx.x;
    if (i >= Nn) return;
    const float* xp = xin + (size_t)i * xstride;
    float xi[Hh];
#pragma unroll
    for (int k = 0; k < Hh; ++k) xi[k] = xp[k];
    float hv[Hh];
#pragma unroll
    for (int j = 0; j < Hh; ++j) {
        float s = 0.f;
#pragma unroll
        for (int k = 0; k < Hh; ++k) s += xi[k] * Wl[k * Hh + j];
        hv[j] = s;
    }
    float ad = 0.f;
#pragma unroll
    for (int j = 0; j < Hh; ++j) ad += hv[j] * adst[j];
    H2F u01, u23, u45, u67;
    u01.h = __floats2half2_rn(hv[0], hv[1]);
    u23.h = __floats2half2_rn(hv[2], hv[3]);
    u45.h = __floats2half2_rn(hv[4], hv[5]);
    u67.h = __floats2half2_rn(hv[6], hv[7]);
    char* rp = P + ((size_t)i << 5);
    *(float4*)rp        = make_float4(u01.f, u23.f, u45.f, u67.f);
    *(float2*)(rp + 16) = make_float2(hv[8], ad);
}

// Per-edge math. x8 is fp32 in the record.
#define AGG_EDGE(F, X8)                                                     \
    {                                                                       \
        H2F u; float2 p;                                                    \
        u.f = (F).x; p = __half22float2(u.h); float x0 = p.x, x1 = p.y;     \
        u.f = (F).y; p = __half22float2(u.h); float x2 = p.x, x3 = p.y;     \
        u.f = (F).z; p = __half22float2(u.h); float x4 = p.x, x5 = p.y;     \
        u.f = (F).w; p = __half22float2(u.h); float x6 = p.x, x7 = p.y;     \
        float x8 = (X8);                                                    \
        float as = x0*s0 + x1*s1 + x2*s2 + x3*s3 + x4*s4                    \
                 + x5*s5 + x6*s6 + x7*s7 + x8*s8;                           \
        float lg = as + c;                                                  \
        lg = lg > 0.f ? lg : 0.2f * lg;                                     \
        float wgt = __expf(lg);                                             \
        a0 += wgt*x0; a1 += wgt*x1; a2 += wgt*x2; a3 += wgt*x3;             \
        a4 += wgt*x4; a5 += wgt*x5; a6 += wgt*x6; a7 += wgt*x7;             \
        a8 += wgt*x8; den += wgt;                                           \
    }

// Oct-per-node gather, LDS-staged CSR, two 2-deep pipelines (4 in flight).
// Single-pass softmax: |logits| << 88 so exp never overflows; ratio exact.
// R10 epilogue fusion: if Pout != null, the q==0 lane also computes the
// NEXT layer's transform (h' = relu_out @ Wn, alpha_d' = h'.adstn) from the
// in-register relu outputs and writes the packed record to Pout. Wn/adstn
// are wave-uniform -> scalar loads. Bit-identical to the standalone
// transform (same FMA order, same inputs).
__global__ __launch_bounds__(256) void k_node_agg(
    const int* __restrict__ rp, const int* __restrict__ csr,
    const char* __restrict__ P, const float* __restrict__ asrc,
    const float* __restrict__ biasl,
    float* __restrict__ jk, int l,
    const float* __restrict__ Wn, const float* __restrict__ adstn,
    char* __restrict__ Pout)
{
    __shared__ int scsr[CAP];
    __shared__ int srp[NPB + 1];
    const int nbase = blockIdx.x * NPB;
    const int t = threadIdx.x;
    if (t <= NPB) srp[t] = rp[nbase + t];   // nbase+NPB <= Nn; rp[Nn] = EP
    __syncthreads();
    const int beg_blk = srp[0];
    const int nseg = srp[NPB] - beg_blk;
    const bool use_lds = (nseg <= CAP);
    if (use_lds)
        for (int j = t; j < nseg; j += 256)
            scsr[j] = __builtin_nontemporal_load(csr + beg_blk + j);
    __syncthreads();

    const float s0 = asrc[0], s1 = asrc[1], s2 = asrc[2], s3 = asrc[3],
                s4 = asrc[4], s5 = asrc[5], s6 = asrc[6], s7 = asrc[7],
                s8 = asrc[8];

    const int ni = t >> 3;          // node within block
    const int q  = t & 7;           // lane within oct
    const int i  = nbase + ni;
    const float c = *(const float*)(P + ((size_t)i << 5) + 20); // own alpha_d
    float a0=0,a1=0,a2=0,a3=0,a4=0,a5=0,a6=0,a7=0,a8=0,den=0;
    if (use_lds) {
        const int iend = srp[ni + 1] - beg_blk;
        int i0 = srp[ni] - beg_blk + q;
        int i1 = i0 + 8;
        int sv0 = (i0 < iend) ? scsr[i0] : 0;
        int sv1 = (i1 < iend) ? scsr[i1] : 0;
        const char* r0 = P + ((size_t)sv0 << 5);
        const char* r1 = P + ((size_t)sv1 << 5);
        float4 F0 = *(const float4*)r0; float e0 = *(const float*)(r0 + 16);
        float4 F1 = *(const float4*)r1; float e1 = *(const float*)(r1 + 16);
        while (i0 < iend) {
            int n0 = i0 + 16, n1 = i1 + 16;
            int sn0 = (n0 < iend) ? scsr[n0] : 0;
            int sn1 = (n1 < iend) ? scsr[n1] : 0;
            const char* rn0 = P + ((size_t)sn0 << 5);
            const char* rn1 = P + ((size_t)sn1 << 5);
            float4 Fn0 = *(const float4*)rn0;
            float en0 = *(const float*)(rn0 + 16);
            float4 Fn1 = *(const float4*)rn1;
            float en1 = *(const float*)(rn1 + 16);
            AGG_EDGE(F0, e0);
            if (i1 < iend) AGG_EDGE(F1, e1);
            F0 = Fn0; e0 = en0; F1 = Fn1; e1 = en1;
            i0 = n0; i1 = n1;
        }
    } else {
        for (int e = srp[ni] + q; e < srp[ni + 1]; e += 8) {
            int s = csr[e];
            const char* r0 = P + ((size_t)s << 5);
            float4 F = *(const float4*)r0;
            float e8 = *(const float*)(r0 + 16);
            AGG_EDGE(F, e8);
        }
    }
#pragma unroll
    for (int m = 1; m <= 4; m <<= 1) {
        a0 += __shfl_xor(a0, m); a1 += __shfl_xor(a1, m);
        a2 += __shfl_xor(a2, m); a3 += __shfl_xor(a3, m);
        a4 += __shfl_xor(a4, m); a5 += __shfl_xor(a5, m);
        a6 += __shfl_xor(a6, m); a7 += __shfl_xor(a7, m);
        a8 += __shfl_xor(a8, m); den += __shfl_xor(den, m);
    }
    if (q == 0) {
        float inv = 1.f / den;          // den >= 1 (self-loop term)
        float o[Hh];
        o[0] = fmaxf(a0*inv + biasl[0], 0.f);
        o[1] = fmaxf(a1*inv + biasl[1], 0.f);
        o[2] = fmaxf(a2*inv + biasl[2], 0.f);
        o[3] = fmaxf(a3*inv + biasl[3], 0.f);
        o[4] = fmaxf(a4*inv + biasl[4], 0.f);
        o[5] = fmaxf(a5*inv + biasl[5], 0.f);
        o[6] = fmaxf(a6*inv + biasl[6], 0.f);
        o[7] = fmaxf(a7*inv + biasl[7], 0.f);
        o[8] = fmaxf(a8*inv + biasl[8], 0.f);
        float* jp = jk + (size_t)l * Nn * Hh + (size_t)i * Hh;
#pragma unroll
        for (int j = 0; j < Hh; ++j) jp[j] = o[j];
        if (Pout) {
            // fused next-layer transform (same FMA order as k_transform)
            float hv[Hh];
#pragma unroll
            for (int j = 0; j < Hh; ++j) {
                float s = 0.f;
#pragma unroll
                for (int k = 0; k < Hh; ++k) s += o[k] * Wn[k * Hh + j];
                hv[j] = s;
            }
            float ad = 0.f;
#pragma unroll
            for (int j = 0; j < Hh; ++j) ad += hv[j] * adstn[j];
            H2F u01, u23, u45, u67;
            u01.h = __floats2half2_rn(hv[0], hv[1]);
            u23.h = __floats2half2_rn(hv[2], hv[3]);
            u45.h = __floats2half2_rn(hv[4], hv[5]);
            u67.h = __floats2half2_rn(hv[6], hv[7]);
            char* rp2 = Pout + ((size_t)i << 5);
            *(float4*)rp2        = make_float4(u01.f, u23.f, u45.f, u67.f);
            *(float2*)(rp2 + 16) = make_float2(hv[8], ad);
        }
    }
}

// ============ pool + fc ============

__global__ __launch_bounds__(256) void k_graph_ptr(
    const int* __restrict__ batch, int* __restrict__ gp)
{
    int i = blockIdx.x * 256 + threadIdx.x;
    if (i >= Nn) return;
    int b = batch[i];
    if (i == 0) {
        for (int g = 0; g <= b; ++g) gp[g] = 0;
    } else {
        int pb = batch[i - 1];
        for (int g = pb + 1; g <= b; ++g) gp[g] = i;
    }
    if (i == Nn - 1) {
        for (int g = b + 1; g <= Gg; ++g) gp[g] = Nn;
    }
}

// Segmented max over layer-major jk [L][Nn][9]; concat order col = l*9+c.
__global__ __launch_bounds__(256) void k_pool_seg(
    const float* __restrict__ jk, const int* __restrict__ gp,
    float* __restrict__ pooled)
{
    int t = blockIdx.x * 256 + threadIdx.x;
    if (t >= Gg * JK) return;
    int g = t / JK, col = t - g * JK;
    int lc = col / Hh, cc = col - lc * Hh;
    const float* bp = jk + (size_t)lc * Nn * Hh + cc;
    int beg = gp[g], end = gp[g + 1];
    float m = 0.f;
    for (int i = beg; i < end; ++i)
        m = fmaxf(m, bp[(size_t)i * Hh]);
    pooled[t] = m;
}

__global__ __launch_bounds__(256) void k_fc(
    const float* __restrict__ pooled, const float* __restrict__ fcw,
    const float* __restrict__ fcb, float* __restrict__ out)
{
    int t = blockIdx.x * blockDim.x + threadIdx.x;
    if (t >= Gg * Cc) return;
    int g = t / Cc, c = t - g * Cc;
    float s = fcb[c];
    const float* pp = pooled + (size_t)g * JK;
#pragma unroll
    for (int j = 0; j < JK; ++j) s += pp[j] * fcw[j * Cc + c];
    out[t] = s;
}

extern "C" void kernel_launch(void* const* d_in, const int* in_sizes, int n_in,
                              void* d_out, int out_size, void* d_ws, size_t ws_size,
                              hipStream_t stream) {
    const float* x      = (const float*)d_in[0];   // [N,9]
    const int*   ei     = (const int*)d_in[1];     // [2,E]
    const int*   batch  = (const int*)d_in[2];     // [N] sorted
    const float* W      = (const float*)d_in[3];   // [L,9,9]
    const float* a_src  = (const float*)d_in[4];   // [L,9]
    const float* a_dst  = (const float*)d_in[5];   // [L,9]
    const float* bias   = (const float*)d_in[6];   // [L,9]
    const float* fc_w   = (const float*)d_in[7];   // [36,2]
    const float* fc_b   = (const float*)d_in[8];   // [2]
    float* out = (float*)d_out;

    // Workspace (~71 MB). histT aliases P0 (dead before transform writes P0:
    // kB completes first in stream order); bucketed aliases jk (dead before
    // agg l=0 writes jk).
    char* P0         = (char*)d_ws;                       // Nn*32B (6.4MB)
    char* P1         = P0 + ((size_t)Nn << 5);            // Nn*32B (6.4MB)
    float* jk        = (float*)(P1 + ((size_t)Nn << 5));  // Nn*JK (28.8MB)
    float* pooled    = jk + (size_t)Nn * JK;              // Gg*JK
    int* row_ptr     = (int*)(pooled + (size_t)Gg * JK);  // Nn+1
    int* gp          = row_ptr + Nn + 1;                  // Gg+1
    int* ctot        = gp + Gg + 1;                       // NCB
    int* cbase       = ctot + NCB;                        // NCB+1
    int* csr_src     = cbase + NCB + 1;                   // EP (26.4MB)
    int* histT       = (int*)P0;                          // aliases P0
    unsigned* bucketed = (unsigned*)jk;                   // aliases jk

    const int* srcp = ei;
    const int* dstp = ei + Ee;

    // CSR build (edge structure is layer-invariant)
    hipMemsetAsync(ctot, 0, NCB * sizeof(int), stream);
    kA_scatter<<<NBLKA, 256, 0, stream>>>(srcp, dstp, ctot, histT, bucketed);
    k_scan    <<<1, 256, 0, stream>>>(ctot, cbase, row_ptr);
    kB_csr    <<<NCB, 1024, 0, stream>>>(bucketed, histT, cbase, row_ptr,
                                         csr_src);

    // Layer 0 transform from x; layers 1..3 records are produced by the
    // previous agg's fused epilogue (P ping-pong).
    k_transform<<<NB, 256, 0, stream>>>(x, Hh, W, a_dst, P0);
    char* Pin = P0;
    char* Pout = P1;
    for (int l = 0; l < Ll; ++l) {
        const bool last = (l == Ll - 1);
        k_node_agg<<<NAB, 256, 0, stream>>>(
            row_ptr, csr_src, Pin, a_src + l * Hh, bias + l * Hh, jk, l,
            last ? nullptr : (W + (l + 1) * Hh * Hh),
            last ? nullptr : (a_dst + (l + 1) * Hh),
            last ? nullptr : Pout);
        char* tmp = Pin; Pin = Pout; Pout = tmp;
    }
    k_graph_ptr<<<NB, 256, 0, stream>>>(batch, gp);
    k_pool_seg<<<(Gg * JK + 255) / 256, 256, 0, stream>>>(jk, gp, pooled);
    k_fc<<<(Gg * Cc + 255) / 256, 256, 0, stream>>>(pooled, fc_w, fc_b, out);
}

// Round 11
// 489.512 us; speedup vs baseline: 1.0544x; 1.0085x over previous
//
#include <hip/hip_runtime.h>
#include <hip/hip_fp16.h>

// Problem constants (from reference)
#define Nn 200000
#define Ee 6400000
#define EP 6600000            // Ee + Nn self loops
#define Hh 9
#define Ll 4
#define Gg 2000
#define Cc 2
#define JK 36                 // Ll * Hh
#define NCB ((Nn + 1023) >> 10) // 196 coarse buckets (1024 nodes each)
#define EPB 8192              // edges per phase-A block
#define NBLKA ((EP + EPB - 1) / EPB) // 806
#define NB ((Nn + 255) / 256) // 782
#define NPB 32                // nodes per k_node_agg block (oct per node)
#define NAB (Nn / NPB)        // 6250 blocks
#define CAP 3072              // staged csr entries per block (12 KB)
#define CAPB 36864            // kB_csr staged entries (144 KB)
#define HTS (NCB + 1)         // histT row stride

union H2F { __half2 h; float f; };

// ========= CSR build: block-major multisplit + per-bucket LDS sort =========
// R11: k_scan dispatch folded into kB (each block re-derives cbase from ctot
// with a single-wave shfl scan — ~1 µs, saves a dispatch+gap). kA unchanged
// (plateaued at ~65 µs across 3 structural attempts).

// Phase A: per-block LDS multisplit, drained BLOCK-MAJOR.
// Payload: src (18b) | dst low 10 bits << 18.
__global__ __launch_bounds__(256) void kA_scatter(
    const int* __restrict__ src, const int* __restrict__ dst,
    int* __restrict__ ctot, int* __restrict__ histT,
    unsigned* __restrict__ bucketed)
{
    __shared__ unsigned pbuf[EPB];        // 32 KB
    __shared__ int lh[4 * NCB];           // per-wave hist -> cursors (3.1 KB)
    __shared__ int s[256];
    int t = threadIdx.x;
    const int w = t >> 6;                 // wave id (0..3)
    for (int j = t; j < 4 * NCB; j += 256) lh[j] = 0;
    __syncthreads();
    const int base = blockIdx.x * EPB;
    const int nseg = min(EPB, EP - base);
    // pass 1: per-wave coarse histogram (dst only)
    for (int j = t; j < nseg; j += 256) {
        int e = base + j;
        int d = (e < Ee) ? dst[e] : (e - Ee);
        atomicAdd(&lh[w * NCB + (d >> 10)], 1);
    }
    __syncthreads();
    // merge 4 wave histograms; scan bin totals; per-wave cursor starts
    int c0 = 0, c1 = 0, c2 = 0, c3 = 0, tot = 0;
    if (t < NCB) {
        c0 = lh[t]; c1 = lh[NCB + t]; c2 = lh[2 * NCB + t]; c3 = lh[3 * NCB + t];
        tot = c0 + c1 + c2 + c3;
    }
    s[t] = tot; __syncthreads();
    for (int off = 1; off < 256; off <<= 1) {
        int u = (t >= off) ? s[t - off] : 0;
        __syncthreads();
        s[t] += u;
        __syncthreads();
    }
    int* hrow = histT + (size_t)blockIdx.x * HTS;
    if (t < NCB) {
        int ex = s[t] - tot;
        lh[t] = ex;
        lh[NCB + t] = ex + c0;
        lh[2 * NCB + t] = ex + c0 + c1;
        lh[3 * NCB + t] = ex + c0 + c1 + c2;
        hrow[t] = ex;
        if (tot) atomicAdd(&ctot[t], tot);
    }
    if (t == 0) hrow[NCB] = nseg;
    __syncthreads();
    // pass 2: scatter into LDS using per-wave cursors
    for (int j = t; j < nseg; j += 256) {
        int e = base + j;
        int sv, d;
        if (e < Ee) { sv = src[e]; d = dst[e]; } else { sv = e - Ee; d = sv; }
        int pos = atomicAdd(&lh[w * NCB + (d >> 10)], 1);
        pbuf[pos] = (unsigned)sv | ((unsigned)(d & 1023) << 18);
    }
    __syncthreads();
    // pass 3: straight coalesced drain, block-major
    for (int j = t; j < nseg; j += 256)
        bucketed[base + j] = pbuf[j];
}

// Phase B: ONE 1024-thread block per coarse bucket. 1024 fine bins,
// barrier-free wave-shfl scan, run bounds preloaded to LDS, 4-way run
// pipelining. R11: cbase derived in-block from ctot (k_scan folded in).
__global__ __launch_bounds__(1024) void kB_csr(
    const unsigned* __restrict__ bucketed, const int* __restrict__ histT,
    const int* __restrict__ ctot, int* __restrict__ row_ptr,
    int* __restrict__ csr_src)
{
    __shared__ int2 hb[NBLKA];            // 6.45 KB run bounds
    __shared__ int bh[1024];              // 4 KB: hist -> cursors
    __shared__ unsigned pbuf[CAPB];       // 144 KB
    __shared__ int wsum[16];
    __shared__ int cb[NCB + 1];           // 788 B: coarse bases (inline scan)
    const int k = blockIdx.x;
    const int t = threadIdx.x;
    const int w = t >> 6, lane = t & 63;  // 16 waves
    bh[t] = 0;
    for (int j = t; j < NBLKA; j += 1024) {
        const int* hrow = histT + (size_t)j * HTS + k;
        hb[j] = make_int2(hrow[0], hrow[1]);
    }
    // inline exclusive scan of ctot[0..NCB) by wave 0 (4 chunks of 64)
    if (t < 64) {
        int acc = 0;
#pragma unroll
        for (int ch = 0; ch < 4; ++ch) {
            int idx = ch * 64 + t;
            int cv = (idx < NCB) ? ctot[idx] : 0;
            int incl = cv;
#pragma unroll
            for (int off = 1; off < 64; off <<= 1) {
                int u = __shfl_up(incl, off);
                if (t >= off) incl += u;
            }
            if (idx < NCB) cb[idx] = acc + incl - cv;
            acc += __shfl(incl, 63);
        }
        if (t == 0) cb[NCB] = EP;
    }
    __syncthreads();
    // pass 1: 1024-bin histogram, 4 runs in flight per wave
    for (int b = w; b < NBLKA; b += 16 * 4) {
        int2 es[4]; unsigned ps[4];
#pragma unroll
        for (int u = 0; u < 4; ++u) {
            int bb = b + 16 * u;
            int2 e = (bb < NBLKA) ? hb[bb] : make_int2(0, 0);
            es[u] = e;
            int j = e.x + lane;
            ps[u] = (j < e.y)
                ? __builtin_nontemporal_load(bucketed + (size_t)bb * EPB + j)
                : 0u;
        }
#pragma unroll
        for (int u = 0; u < 4; ++u) {
            int bb = b + 16 * u;
            if (bb >= NBLKA) break;
            int j = es[u].x + lane;
            if (j < es[u].y) atomicAdd(&bh[(ps[u] >> 18) & 1023], 1);
            for (j += 64; j < es[u].y; j += 64) {
                unsigned p = __builtin_nontemporal_load(
                    bucketed + (size_t)bb * EPB + j);
                atomicAdd(&bh[(p >> 18) & 1023], 1);
            }
        }
    }
    __syncthreads();
    // exclusive scan of 1024 bins: wave shfl scan + cross-wave bases
    int v = bh[t];
    int incl = v;
#pragma unroll
    for (int off = 1; off < 64; off <<= 1) {
        int u = __shfl_up(incl, off);
        if (lane >= off) incl += u;
    }
    if (lane == 63) wsum[w] = incl;
    __syncthreads();
    if (t == 0) {
        int acc = 0;
#pragma unroll
        for (int i2 = 0; i2 < 16; ++i2) { int x = wsum[i2]; wsum[i2] = acc; acc += x; }
    }
    __syncthreads();
    int excl = wsum[w] + incl - v;
    const int base_k = cb[k];
    const int nseg_b = cb[k + 1] - base_k;
    const int node = (k << 10) + t;
    if (node < Nn) row_ptr[node] = base_k + excl;
    if (k == 0 && t == 0) row_ptr[Nn] = EP;
    bh[t] = excl;                         // pbuf-relative cursor
    __syncthreads();
    const bool fit = (nseg_b <= CAPB);
    if (fit) {
        // pass 2: scatter into LDS pbuf, 4 runs in flight per wave
        for (int b = w; b < NBLKA; b += 16 * 4) {
            int2 es[4]; unsigned ps[4];
#pragma unroll
            for (int u = 0; u < 4; ++u) {
                int bb = b + 16 * u;
                int2 e = (bb < NBLKA) ? hb[bb] : make_int2(0, 0);
                es[u] = e;
                int j = e.x + lane;
                ps[u] = (j < e.y)
                    ? __builtin_nontemporal_load(bucketed + (size_t)bb * EPB + j)
                    : 0u;
            }
#pragma unroll
            for (int u = 0; u < 4; ++u) {
                int bb = b + 16 * u;
                if (bb >= NBLKA) break;
                int j = es[u].x + lane;
                if (j < es[u].y) {
                    unsigned p = ps[u];
                    int pos = atomicAdd(&bh[(p >> 18) & 1023], 1);
                    pbuf[pos] = p & 0x3FFFFu;
                }
                for (j += 64; j < es[u].y; j += 64) {
                    unsigned p = __builtin_nontemporal_load(
                        bucketed + (size_t)bb * EPB + j);
                    int pos = atomicAdd(&bh[(p >> 18) & 1023], 1);
                    pbuf[pos] = p & 0x3FFFFu;
                }
            }
        }
        __syncthreads();
        // fully-coalesced drain
        for (int j = t; j < nseg_b; j += 1024)
            csr_src[base_k + j] = (int)pbuf[j];
    } else {
        // fallback: direct global scatter (statistically never)
        for (int b = w; b < NBLKA; b += 16) {
            int2 e = hb[b];
            int rb = b * EPB;
            for (int j = e.x + lane; j < e.y; j += 64) {
                unsigned p = bucketed[rb + j];
                int pos = base_k + atomicAdd(&bh[(p >> 18) & 1023], 1);
                csr_src[pos] = (int)(p & 0x3FFFFu);
            }
        }
    }
}

// ============ per-layer kernels ============

// ONE 32B packed record per node:
//   P[i] @ i*32: [0..15] h0..h7 as 4x half2, [16..19] h8 fp32,
//                [20..23] alpha_d fp32, [24..31] pad.
// k_transform runs ONCE (layer 0, from x). Layers 1..3 records come from the
// previous agg's fused epilogue (P ping-pong).
__global__ __launch_bounds__(256) void k_transform(
    const float* __restrict__ xin, int xstride,
    const float* __restrict__ Wl,
    const float* __restrict__ adst,
    char* __restrict__ P)
{
    int i = blockIdx.x * blockDim.x + threadIdx.x;
    if (i >= Nn) return;
    const float* xp = xin + (size_t)i * xstride;
    float xi[Hh];
#pragma unroll
    for (int k = 0; k < Hh; ++k) xi[k] = xp[k];
    float hv[Hh];
#pragma unroll
    for (int j = 0; j < Hh; ++j) {
        float s = 0.f;
#pragma unroll
        for (int k = 0; k < Hh; ++k) s += xi[k] * Wl[k * Hh + j];
        hv[j] = s;
    }
    float ad = 0.f;
#pragma unroll
    for (int j = 0; j < Hh; ++j) ad += hv[j] * adst[j];
    H2F u01, u23, u45, u67;
    u01.h = __floats2half2_rn(hv[0], hv[1]);
    u23.h = __floats2half2_rn(hv[2], hv[3]);
    u45.h = __floats2half2_rn(hv[4], hv[5]);
    u67.h = __floats2half2_rn(hv[6], hv[7]);
    char* rp = P + ((size_t)i << 5);
    *(float4*)rp        = make_float4(u01.f, u23.f, u45.f, u67.f);
    *(float2*)(rp + 16) = make_float2(hv[8], ad);
}

// Per-edge math. x8 is fp32 in the record.
#define AGG_EDGE(F, X8)                                                     \
    {                                                                       \
        H2F u; float2 p;                                                    \
        u.f = (F).x; p = __half22float2(u.h); float x0 = p.x, x1 = p.y;     \
        u.f = (F).y; p = __half22float2(u.h); float x2 = p.x, x3 = p.y;     \
        u.f = (F).z; p = __half22float2(u.h); float x4 = p.x, x5 = p.y;     \
        u.f = (F).w; p = __half22float2(u.h); float x6 = p.x, x7 = p.y;     \
        float x8 = (X8);                                                    \
        float as = x0*s0 + x1*s1 + x2*s2 + x3*s3 + x4*s4                    \
                 + x5*s5 + x6*s6 + x7*s7 + x8*s8;                           \
        float lg = as + c;                                                  \
        lg = lg > 0.f ? lg : 0.2f * lg;                                     \
        float wgt = __expf(lg);                                             \
        a0 += wgt*x0; a1 += wgt*x1; a2 += wgt*x2; a3 += wgt*x3;             \
        a4 += wgt*x4; a5 += wgt*x5; a6 += wgt*x6; a7 += wgt*x7;             \
        a8 += wgt*x8; den += wgt;                                           \
    }

// Oct-per-node gather, LDS-staged CSR, two 2-deep pipelines (4 in flight).
// Single-pass softmax: |logits| << 88 so exp never overflows; ratio exact.
// Epilogue fusion: if Pout != null, q==0 also computes next layer's
// transform from the in-register relu outputs (bit-identical FMA order).
__global__ __launch_bounds__(256) void k_node_agg(
    const int* __restrict__ rp, const int* __restrict__ csr,
    const char* __restrict__ P, const float* __restrict__ asrc,
    const float* __restrict__ biasl,
    float* __restrict__ jk, int l,
    const float* __restrict__ Wn, const float* __restrict__ adstn,
    char* __restrict__ Pout)
{
    __shared__ int scsr[CAP];
    __shared__ int srp[NPB + 1];
    const int nbase = blockIdx.x * NPB;
    const int t = threadIdx.x;
    if (t <= NPB) srp[t] = rp[nbase + t];   // nbase+NPB <= Nn; rp[Nn] = EP
    __syncthreads();
    const int beg_blk = srp[0];
    const int nseg = srp[NPB] - beg_blk;
    const bool use_lds = (nseg <= CAP);
    if (use_lds)
        for (int j = t; j < nseg; j += 256)
            scsr[j] = __builtin_nontemporal_load(csr + beg_blk + j);
    __syncthreads();

    const float s0 = asrc[0], s1 = asrc[1], s2 = asrc[2], s3 = asrc[3],
                s4 = asrc[4], s5 = asrc[5], s6 = asrc[6], s7 = asrc[7],
                s8 = asrc[8];

    const int ni = t >> 3;          // node within block
    const int q  = t & 7;           // lane within oct
    const int i  = nbase + ni;
    const float c = *(const float*)(P + ((size_t)i << 5) + 20); // own alpha_d
    float a0=0,a1=0,a2=0,a3=0,a4=0,a5=0,a6=0,a7=0,a8=0,den=0;
    if (use_lds) {
        const int iend = srp[ni + 1] - beg_blk;
        int i0 = srp[ni] - beg_blk + q;
        int i1 = i0 + 8;
        int sv0 = (i0 < iend) ? scsr[i0] : 0;
        int sv1 = (i1 < iend) ? scsr[i1] : 0;
        const char* r0 = P + ((size_t)sv0 << 5);
        const char* r1 = P + ((size_t)sv1 << 5);
        float4 F0 = *(const float4*)r0; float e0 = *(const float*)(r0 + 16);
        float4 F1 = *(const float4*)r1; float e1 = *(const float*)(r1 + 16);
        while (i0 < iend) {
            int n0 = i0 + 16, n1 = i1 + 16;
            int sn0 = (n0 < iend) ? scsr[n0] : 0;
            int sn1 = (n1 < iend) ? scsr[n1] : 0;
            const char* rn0 = P + ((size_t)sn0 << 5);
            const char* rn1 = P + ((size_t)sn1 << 5);
            float4 Fn0 = *(const float4*)rn0;
            float en0 = *(const float*)(rn0 + 16);
            float4 Fn1 = *(const float4*)rn1;
            float en1 = *(const float*)(rn1 + 16);
            AGG_EDGE(F0, e0);
            if (i1 < iend) AGG_EDGE(F1, e1);
            F0 = Fn0; e0 = en0; F1 = Fn1; e1 = en1;
            i0 = n0; i1 = n1;
        }
    } else {
        for (int e = srp[ni] + q; e < srp[ni + 1]; e += 8) {
            int s = csr[e];
            const char* r0 = P + ((size_t)s << 5);
            float4 F = *(const float4*)r0;
            float e8 = *(const float*)(r0 + 16);
            AGG_EDGE(F, e8);
        }
    }
#pragma unroll
    for (int m = 1; m <= 4; m <<= 1) {
        a0 += __shfl_xor(a0, m); a1 += __shfl_xor(a1, m);
        a2 += __shfl_xor(a2, m); a3 += __shfl_xor(a3, m);
        a4 += __shfl_xor(a4, m); a5 += __shfl_xor(a5, m);
        a6 += __shfl_xor(a6, m); a7 += __shfl_xor(a7, m);
        a8 += __shfl_xor(a8, m); den += __shfl_xor(den, m);
    }
    if (q == 0) {
        float inv = 1.f / den;          // den >= 1 (self-loop term)
        float o[Hh];
        o[0] = fmaxf(a0*inv + biasl[0], 0.f);
        o[1] = fmaxf(a1*inv + biasl[1], 0.f);
        o[2] = fmaxf(a2*inv + biasl[2], 0.f);
        o[3] = fmaxf(a3*inv + biasl[3], 0.f);
        o[4] = fmaxf(a4*inv + biasl[4], 0.f);
        o[5] = fmaxf(a5*inv + biasl[5], 0.f);
        o[6] = fmaxf(a6*inv + biasl[6], 0.f);
        o[7] = fmaxf(a7*inv + biasl[7], 0.f);
        o[8] = fmaxf(a8*inv + biasl[8], 0.f);
        float* jp = jk + (size_t)l * Nn * Hh + (size_t)i * Hh;
#pragma unroll
        for (int j = 0; j < Hh; ++j) jp[j] = o[j];
        if (Pout) {
            // fused next-layer transform (same FMA order as k_transform)
            float hv[Hh];
#pragma unroll
            for (int j = 0; j < Hh; ++j) {
                float s = 0.f;
#pragma unroll
                for (int k = 0; k < Hh; ++k) s += o[k] * Wn[k * Hh + j];
                hv[j] = s;
            }
            float ad = 0.f;
#pragma unroll
            for (int j = 0; j < Hh; ++j) ad += hv[j] * adstn[j];
            H2F u01, u23, u45, u67;
            u01.h = __floats2half2_rn(hv[0], hv[1]);
            u23.h = __floats2half2_rn(hv[2], hv[3]);
            u45.h = __floats2half2_rn(hv[4], hv[5]);
            u67.h = __floats2half2_rn(hv[6], hv[7]);
            char* rp2 = Pout + ((size_t)i << 5);
            *(float4*)rp2        = make_float4(u01.f, u23.f, u45.f, u67.f);
            *(float2*)(rp2 + 16) = make_float2(hv[8], ad);
        }
    }
}

// ============ fused pool + fc ============

// R11: one 64-thread block per graph. Two binary searches over the sorted
// batch array replace k_graph_ptr's gp[] entirely; 36 lanes pool their
// (layer,channel) column over the node range; 2 lanes do the fc dot.
// Post-relu values >= 0 and m=0 init reproduces the isfinite->0 guard.
__global__ __launch_bounds__(64) void k_pool_fc(
    const float* __restrict__ jk, const int* __restrict__ batch,
    const float* __restrict__ fcw, const float* __restrict__ fcb,
    float* __restrict__ out)
{
    __shared__ float pl[JK];
    __shared__ int bounds[2];
    const int g = blockIdx.x;
    const int t = threadIdx.x;
    if (t < 2) {
        int target = g + t;
        int lo = 0, hi = Nn;
        while (lo < hi) {               // lower_bound(batch, target)
            int mid = (lo + hi) >> 1;
            if (batch[mid] < target) lo = mid + 1; else hi = mid;
        }
        bounds[t] = lo;
    }
    __syncthreads();
    const int beg = bounds[0], end = bounds[1];
    if (t < JK) {
        int lc = t / Hh, cc = t - lc * Hh;
        const float* bp = jk + (size_t)lc * Nn * Hh + cc;
        float m = 0.f;
        for (int i = beg; i < end; ++i)
            m = fmaxf(m, bp[(size_t)i * Hh]);
        pl[t] = m;
    }
    __syncthreads();
    if (t < Cc) {
        float s = fcb[t];
#pragma unroll
        for (int j = 0; j < JK; ++j) s += pl[j] * fcw[j * Cc + t];
        out[g * Cc + t] = s;
    }
}

extern "C" void kernel_launch(void* const* d_in, const int* in_sizes, int n_in,
                              void* d_out, int out_size, void* d_ws, size_t ws_size,
                              hipStream_t stream) {
    const float* x      = (const float*)d_in[0];   // [N,9]
    const int*   ei     = (const int*)d_in[1];     // [2,E]
    const int*   batch  = (const int*)d_in[2];     // [N] sorted
    const float* W      = (const float*)d_in[3];   // [L,9,9]
    const float* a_src  = (const float*)d_in[4];   // [L,9]
    const float* a_dst  = (const float*)d_in[5];   // [L,9]
    const float* bias   = (const float*)d_in[6];   // [L,9]
    const float* fc_w   = (const float*)d_in[7];   // [36,2]
    const float* fc_b   = (const float*)d_in[8];   // [2]
    float* out = (float*)d_out;

    // Workspace (~71 MB). histT aliases P0 (dead before transform writes P0);
    // bucketed aliases jk (dead before agg l=0 writes jk).
    char* P0         = (char*)d_ws;                       // Nn*32B (6.4MB)
    char* P1         = P0 + ((size_t)Nn << 5);            // Nn*32B (6.4MB)
    float* jk        = (float*)(P1 + ((size_t)Nn << 5));  // Nn*JK (28.8MB)
    int* row_ptr     = (int*)(jk + (size_t)Nn * JK);      // Nn+1
    int* ctot        = row_ptr + Nn + 1;                  // NCB
    int* csr_src     = ctot + NCB;                        // EP (26.4MB)
    int* histT       = (int*)P0;                          // aliases P0
    unsigned* bucketed = (unsigned*)jk;                   // aliases jk

    const int* srcp = ei;
    const int* dstp = ei + Ee;

    // CSR build (edge structure is layer-invariant). 3 dispatches + memset.
    hipMemsetAsync(ctot, 0, NCB * sizeof(int), stream);
    kA_scatter<<<NBLKA, 256, 0, stream>>>(srcp, dstp, ctot, histT, bucketed);
    kB_csr    <<<NCB, 1024, 0, stream>>>(bucketed, histT, ctot, row_ptr,
                                         csr_src);

    // Layer 0 transform from x; layers 1..3 records come from the previous
    // agg's fused epilogue (P ping-pong).
    k_transform<<<NB, 256, 0, stream>>>(x, Hh, W, a_dst, P0);
    char* Pin = P0;
    char* Pout = P1;
    for (int l = 0; l < Ll; ++l) {
        const bool last = (l == Ll - 1);
        k_node_agg<<<NAB, 256, 0, stream>>>(
            row_ptr, csr_src, Pin, a_src + l * Hh, bias + l * Hh, jk, l,
            last ? nullptr : (W + (l + 1) * Hh * Hh),
            last ? nullptr : (a_dst + (l + 1) * Hh),
            last ? nullptr : Pout);
        char* tmp = Pin; Pin = Pout; Pout = tmp;
    }
    k_pool_fc<<<Gg, 64, 0, stream>>>(jk, batch, fc_w, fc_b, out);
}

// Round 13
// 485.023 us; speedup vs baseline: 1.0642x; 1.0093x over previous
//
#include <hip/hip_runtime.h>
#include <hip/hip_fp16.h>

// Problem constants (from reference)
#define Nn 200000
#define Ee 6400000
#define EP 6600000            // Ee + Nn self loops
#define Hh 9
#define Ll 4
#define Gg 2000
#define Cc 2
#define JK 36                 // Ll * Hh
#define NCB ((Nn + 1023) >> 10) // 196 coarse buckets (1024 nodes each)
#define EPB 8192              // edges per phase-A block
#define NBLKA ((EP + EPB - 1) / EPB) // 806
#define NB ((Nn + 255) / 256) // 782
#define NPB 32                // nodes per k_node_agg block (oct per node)
#define NAB (Nn / NPB)        // 6250 blocks
#define CAP 3072              // staged csr entries per block (12 KB)
#define CAPB 36864            // kB_csr staged entries (144 KB)
#define HTS (NCB + 1)         // histT row stride

union H2F { __half2 h; float f; };

// Shared transform body: h = x@W, alpha_d = h.adst, pack 32B record.
__device__ __forceinline__ void transform_node(
    const float* __restrict__ xp, const float* __restrict__ Wl,
    const float* __restrict__ adst, char* __restrict__ rp)
{
    float xi[Hh];
#pragma unroll
    for (int k = 0; k < Hh; ++k) xi[k] = xp[k];
    float hv[Hh];
#pragma unroll
    for (int j = 0; j < Hh; ++j) {
        float s = 0.f;
#pragma unroll
        for (int k = 0; k < Hh; ++k) s += xi[k] * Wl[k * Hh + j];
        hv[j] = s;
    }
    float ad = 0.f;
#pragma unroll
    for (int j = 0; j < Hh; ++j) ad += hv[j] * adst[j];
    H2F u01, u23, u45, u67;
    u01.h = __floats2half2_rn(hv[0], hv[1]);
    u23.h = __floats2half2_rn(hv[2], hv[3]);
    u45.h = __floats2half2_rn(hv[4], hv[5]);
    u67.h = __floats2half2_rn(hv[6], hv[7]);
    *(float4*)rp        = make_float4(u01.f, u23.f, u45.f, u67.f);
    *(float2*)(rp + 16) = make_float2(hv[8], ad);
}

// ========= CSR build: block-major multisplit + per-bucket LDS sort =========
// R12: layer-0 transform FUSED into the kA dispatch as extra blocks (the two
// are data-independent; on one stream they'd serialize — extra blocks fill
// the idle capacity of kA's latency-bound phases). histT moved into jk's
// tail so P0 no longer aliases it.

// Phase A: per-block LDS multisplit, drained BLOCK-MAJOR.
// Payload: src (18b) | dst low 10 bits << 18.
__global__ __launch_bounds__(256) void kA_scatter(
    const int* __restrict__ src, const int* __restrict__ dst,
    int* __restrict__ ctot, int* __restrict__ histT,
    unsigned* __restrict__ bucketed,
    const float* __restrict__ x, const float* __restrict__ W0,
    const float* __restrict__ adst0, char* __restrict__ P0)
{
    __shared__ unsigned pbuf[EPB];        // 32 KB
    __shared__ int lh[4 * NCB];           // per-wave hist -> cursors (3.1 KB)
    __shared__ int s[256];
    int t = threadIdx.x;
    // transform blocks (fused layer-0 transform, independent of CSR build)
    if (blockIdx.x >= NBLKA) {
        int i = (blockIdx.x - NBLKA) * 256 + t;
        if (i < Nn)
            transform_node(x + (size_t)i * Hh, W0, adst0, P0 + ((size_t)i << 5));
        return;
    }
    const int w = t >> 6;                 // wave id (0..3)
    for (int j = t; j < 4 * NCB; j += 256) lh[j] = 0;
    __syncthreads();
    const int base = blockIdx.x * EPB;
    const int nseg = min(EPB, EP - base);
    // pass 1: per-wave coarse histogram (dst only)
    for (int j = t; j < nseg; j += 256) {
        int e = base + j;
        int d = (e < Ee) ? dst[e] : (e - Ee);
        atomicAdd(&lh[w * NCB + (d >> 10)], 1);
    }
    __syncthreads();
    // merge 4 wave histograms; scan bin totals; per-wave cursor starts
    int c0 = 0, c1 = 0, c2 = 0, c3 = 0, tot = 0;
    if (t < NCB) {
        c0 = lh[t]; c1 = lh[NCB + t]; c2 = lh[2 * NCB + t]; c3 = lh[3 * NCB + t];
        tot = c0 + c1 + c2 + c3;
    }
    s[t] = tot; __syncthreads();
    for (int off = 1; off < 256; off <<= 1) {
        int u = (t >= off) ? s[t - off] : 0;
        __syncthreads();
        s[t] += u;
        __syncthreads();
    }
    int* hrow = histT + (size_t)blockIdx.x * HTS;
    if (t < NCB) {
        int ex = s[t] - tot;
        lh[t] = ex;
        lh[NCB + t] = ex + c0;
        lh[2 * NCB + t] = ex + c0 + c1;
        lh[3 * NCB + t] = ex + c0 + c1 + c2;
        hrow[t] = ex;
        if (tot) atomicAdd(&ctot[t], tot);
    }
    if (t == 0) hrow[NCB] = nseg;
    __syncthreads();
    // pass 2: scatter into LDS using per-wave cursors
    for (int j = t; j < nseg; j += 256) {
        int e = base + j;
        int sv, d;
        if (e < Ee) { sv = src[e]; d = dst[e]; } else { sv = e - Ee; d = sv; }
        int pos = atomicAdd(&lh[w * NCB + (d >> 10)], 1);
        pbuf[pos] = (unsigned)sv | ((unsigned)(d & 1023) << 18);
    }
    __syncthreads();
    // pass 3: straight coalesced drain, block-major
    for (int j = t; j < nseg; j += 256)
        bucketed[base + j] = pbuf[j];
}

// Phase B: ONE 1024-thread block per coarse bucket. 1024 fine bins,
// barrier-free wave-shfl scan, run bounds preloaded to LDS, 4-way run
// pipelining. cbase derived in-block from ctot (k_scan folded in).
__global__ __launch_bounds__(1024) void kB_csr(
    const unsigned* __restrict__ bucketed, const int* __restrict__ histT,
    const int* __restrict__ ctot, int* __restrict__ row_ptr,
    int* __restrict__ csr_src)
{
    __shared__ int2 hb[NBLKA];            // 6.45 KB run bounds
    __shared__ int bh[1024];              // 4 KB: hist -> cursors
    __shared__ unsigned pbuf[CAPB];       // 144 KB
    __shared__ int wsum[16];
    __shared__ int cb[NCB + 1];           // 788 B: coarse bases (inline scan)
    const int k = blockIdx.x;
    const int t = threadIdx.x;
    const int w = t >> 6, lane = t & 63;  // 16 waves
    bh[t] = 0;
    for (int j = t; j < NBLKA; j += 1024) {
        const int* hrow = histT + (size_t)j * HTS + k;
        hb[j] = make_int2(hrow[0], hrow[1]);
    }
    // inline exclusive scan of ctot[0..NCB) by wave 0 (4 chunks of 64)
    if (t < 64) {
        int acc = 0;
#pragma unroll
        for (int ch = 0; ch < 4; ++ch) {
            int idx = ch * 64 + t;
            int cv = (idx < NCB) ? ctot[idx] : 0;
            int incl = cv;
#pragma unroll
            for (int off = 1; off < 64; off <<= 1) {
                int u = __shfl_up(incl, off);
                if (t >= off) incl += u;
            }
            if (idx < NCB) cb[idx] = acc + incl - cv;
            acc += __shfl(incl, 63);
        }
        if (t == 0) cb[NCB] = EP;
    }
    __syncthreads();
    // pass 1: 1024-bin histogram, 4 runs in flight per wave
    for (int b = w; b < NBLKA; b += 16 * 4) {
        int2 es[4]; unsigned ps[4];
#pragma unroll
        for (int u = 0; u < 4; ++u) {
            int bb = b + 16 * u;
            int2 e = (bb < NBLKA) ? hb[bb] : make_int2(0, 0);
            es[u] = e;
            int j = e.x + lane;
            ps[u] = (j < e.y)
                ? __builtin_nontemporal_load(bucketed + (size_t)bb * EPB + j)
                : 0u;
        }
#pragma unroll
        for (int u = 0; u < 4; ++u) {
            int bb = b + 16 * u;
            if (bb >= NBLKA) break;
            int j = es[u].x + lane;
            if (j < es[u].y) atomicAdd(&bh[(ps[u] >> 18) & 1023], 1);
            for (j += 64; j < es[u].y; j += 64) {
                unsigned p = __builtin_nontemporal_load(
                    bucketed + (size_t)bb * EPB + j);
                atomicAdd(&bh[(p >> 18) & 1023], 1);
            }
        }
    }
    __syncthreads();
    // exclusive scan of 1024 bins: wave shfl scan + cross-wave bases
    int v = bh[t];
    int incl = v;
#pragma unroll
    for (int off = 1; off < 64; off <<= 1) {
        int u = __shfl_up(incl, off);
        if (lane >= off) incl += u;
    }
    if (lane == 63) wsum[w] = incl;
    __syncthreads();
    if (t == 0) {
        int acc = 0;
#pragma unroll
        for (int i2 = 0; i2 < 16; ++i2) { int x = wsum[i2]; wsum[i2] = acc; acc += x; }
    }
    __syncthreads();
    int excl = wsum[w] + incl - v;
    const int base_k = cb[k];
    const int nseg_b = cb[k + 1] - base_k;
    const int node = (k << 10) + t;
    if (node < Nn) row_ptr[node] = base_k + excl;
    if (k == 0 && t == 0) row_ptr[Nn] = EP;
    bh[t] = excl;                         // pbuf-relative cursor
    __syncthreads();
    const bool fit = (nseg_b <= CAPB);
    if (fit) {
        // pass 2: scatter into LDS pbuf, 4 runs in flight per wave
        for (int b = w; b < NBLKA; b += 16 * 4) {
            int2 es[4]; unsigned ps[4];
#pragma unroll
            for (int u = 0; u < 4; ++u) {
                int bb = b + 16 * u;
                int2 e = (bb < NBLKA) ? hb[bb] : make_int2(0, 0);
                es[u] = e;
                int j = e.x + lane;
                ps[u] = (j < e.y)
                    ? __builtin_nontemporal_load(bucketed + (size_t)bb * EPB + j)
                    : 0u;
            }
#pragma unroll
            for (int u = 0; u < 4; ++u) {
                int bb = b + 16 * u;
                if (bb >= NBLKA) break;
                int j = es[u].x + lane;
                if (j < es[u].y) {
                    unsigned p = ps[u];
                    int pos = atomicAdd(&bh[(p >> 18) & 1023], 1);
                    pbuf[pos] = p & 0x3FFFFu;
                }
                for (j += 64; j < es[u].y; j += 64) {
                    unsigned p = __builtin_nontemporal_load(
                        bucketed + (size_t)bb * EPB + j);
                    int pos = atomicAdd(&bh[(p >> 18) & 1023], 1);
                    pbuf[pos] = p & 0x3FFFFu;
                }
            }
        }
        __syncthreads();
        // fully-coalesced drain
        for (int j = t; j < nseg_b; j += 1024)
            csr_src[base_k + j] = (int)pbuf[j];
    } else {
        // fallback: direct global scatter (statistically never)
        for (int b = w; b < NBLKA; b += 16) {
            int2 e = hb[b];
            int rb = b * EPB;
            for (int j = e.x + lane; j < e.y; j += 64) {
                unsigned p = bucketed[rb + j];
                int pos = base_k + atomicAdd(&bh[(p >> 18) & 1023], 1);
                csr_src[pos] = (int)(p & 0x3FFFFu);
            }
        }
    }
}

// ============ per-layer agg (transform fused into epilogue) ============

// ONE 32B packed record per node:
//   P[i] @ i*32: [0..15] h0..h7 as 4x half2, [16..19] h8 fp32,
//                [20..23] alpha_d fp32, [24..31] pad.
// Layer-0 records come from the kA-fused transform; layers 1..3 from the
// previous agg's fused epilogue (P ping-pong).

// Per-edge math. x8 is fp32 in the record.
#define AGG_EDGE(F, X8)                                                     \
    {                                                                       \
        H2F u; float2 p;                                                    \
        u.f = (F).x; p = __half22float2(u.h); float x0 = p.x, x1 = p.y;     \
        u.f = (F).y; p = __half22float2(u.h); float x2 = p.x, x3 = p.y;     \
        u.f = (F).z; p = __half22float2(u.h); float x4 = p.x, x5 = p.y;     \
        u.f = (F).w; p = __half22float2(u.h); float x6 = p.x, x7 = p.y;     \
        float x8 = (X8);                                                    \
        float as = x0*s0 + x1*s1 + x2*s2 + x3*s3 + x4*s4                    \
                 + x5*s5 + x6*s6 + x7*s7 + x8*s8;                           \
        float lg = as + c;                                                  \
        lg = lg > 0.f ? lg : 0.2f * lg;                                     \
        float wgt = __expf(lg);                                             \
        a0 += wgt*x0; a1 += wgt*x1; a2 += wgt*x2; a3 += wgt*x3;             \
        a4 += wgt*x4; a5 += wgt*x5; a6 += wgt*x6; a7 += wgt*x7;             \
        a8 += wgt*x8; den += wgt;                                           \
    }

// Oct-per-node gather, LDS-staged CSR, two 2-deep pipelines (4 in flight).
// Single-pass softmax: |logits| << 88 so exp never overflows; ratio exact.
__global__ __launch_bounds__(256) void k_node_agg(
    const int* __restrict__ rp, const int* __restrict__ csr,
    const char* __restrict__ P, const float* __restrict__ asrc,
    const float* __restrict__ biasl,
    float* __restrict__ jk, int l,
    const float* __restrict__ Wn, const float* __restrict__ adstn,
    char* __restrict__ Pout)
{
    __shared__ int scsr[CAP];
    __shared__ int srp[NPB + 1];
    const int nbase = blockIdx.x * NPB;
    const int t = threadIdx.x;
    if (t <= NPB) srp[t] = rp[nbase + t];   // nbase+NPB <= Nn; rp[Nn] = EP
    __syncthreads();
    const int beg_blk = srp[0];
    const int nseg = srp[NPB] - beg_blk;
    const bool use_lds = (nseg <= CAP);
    if (use_lds)
        for (int j = t; j < nseg; j += 256)
            scsr[j] = __builtin_nontemporal_load(csr + beg_blk + j);
    __syncthreads();

    const float s0 = asrc[0], s1 = asrc[1], s2 = asrc[2], s3 = asrc[3],
                s4 = asrc[4], s5 = asrc[5], s6 = asrc[6], s7 = asrc[7],
                s8 = asrc[8];

    const int ni = t >> 3;          // node within block
    const int q  = t & 7;           // lane within oct
    const int i  = nbase + ni;
    const float c = *(const float*)(P + ((size_t)i << 5) + 20); // own alpha_d
    float a0=0,a1=0,a2=0,a3=0,a4=0,a5=0,a6=0,a7=0,a8=0,den=0;
    if (use_lds) {
        const int iend = srp[ni + 1] - beg_blk;
        int i0 = srp[ni] - beg_blk + q;
        int i1 = i0 + 8;
        int sv0 = (i0 < iend) ? scsr[i0] : 0;
        int sv1 = (i1 < iend) ? scsr[i1] : 0;
        const char* r0 = P + ((size_t)sv0 << 5);
        const char* r1 = P + ((size_t)sv1 << 5);
        float4 F0 = *(const float4*)r0; float e0 = *(const float*)(r0 + 16);
        float4 F1 = *(const float4*)r1; float e1 = *(const float*)(r1 + 16);
        while (i0 < iend) {
            int n0 = i0 + 16, n1 = i1 + 16;
            int sn0 = (n0 < iend) ? scsr[n0] : 0;
            int sn1 = (n1 < iend) ? scsr[n1] : 0;
            const char* rn0 = P + ((size_t)sn0 << 5);
            const char* rn1 = P + ((size_t)sn1 << 5);
            float4 Fn0 = *(const float4*)rn0;
            float en0 = *(const float*)(rn0 + 16);
            float4 Fn1 = *(const float4*)rn1;
            float en1 = *(const float*)(rn1 + 16);
            AGG_EDGE(F0, e0);
            if (i1 < iend) AGG_EDGE(F1, e1);
            F0 = Fn0; e0 = en0; F1 = Fn1; e1 = en1;
            i0 = n0; i1 = n1;
        }
    } else {
        for (int e = srp[ni] + q; e < srp[ni + 1]; e += 8) {
            int s = csr[e];
            const char* r0 = P + ((size_t)s << 5);
            float4 F = *(const float4*)r0;
            float e8 = *(const float*)(r0 + 16);
            AGG_EDGE(F, e8);
        }
    }
#pragma unroll
    for (int m = 1; m <= 4; m <<= 1) {
        a0 += __shfl_xor(a0, m); a1 += __shfl_xor(a1, m);
        a2 += __shfl_xor(a2, m); a3 += __shfl_xor(a3, m);
        a4 += __shfl_xor(a4, m); a5 += __shfl_xor(a5, m);
        a6 += __shfl_xor(a6, m); a7 += __shfl_xor(a7, m);
        a8 += __shfl_xor(a8, m); den += __shfl_xor(den, m);
    }
    if (q == 0) {
        float inv = 1.f / den;          // den >= 1 (self-loop term)
        float o[Hh];
        o[0] = fmaxf(a0*inv + biasl[0], 0.f);
        o[1] = fmaxf(a1*inv + biasl[1], 0.f);
        o[2] = fmaxf(a2*inv + biasl[2], 0.f);
        o[3] = fmaxf(a3*inv + biasl[3], 0.f);
        o[4] = fmaxf(a4*inv + biasl[4], 0.f);
        o[5] = fmaxf(a5*inv + biasl[5], 0.f);
        o[6] = fmaxf(a6*inv + biasl[6], 0.f);
        o[7] = fmaxf(a7*inv + biasl[7], 0.f);
        o[8] = fmaxf(a8*inv + biasl[8], 0.f);
        float* jp = jk + (size_t)l * Nn * Hh + (size_t)i * Hh;
#pragma unroll
        for (int j = 0; j < Hh; ++j) jp[j] = o[j];
        if (Pout) {
            // fused next-layer transform (same FMA order as transform_node)
            float hv[Hh];
#pragma unroll
            for (int j = 0; j < Hh; ++j) {
                float s = 0.f;
#pragma unroll
                for (int k = 0; k < Hh; ++k) s += o[k] * Wn[k * Hh + j];
                hv[j] = s;
            }
            float ad = 0.f;
#pragma unroll
            for (int j = 0; j < Hh; ++j) ad += hv[j] * adstn[j];
            H2F u01, u23, u45, u67;
            u01.h = __floats2half2_rn(hv[0], hv[1]);
            u23.h = __floats2half2_rn(hv[2], hv[3]);
            u45.h = __floats2half2_rn(hv[4], hv[5]);
            u67.h = __floats2half2_rn(hv[6], hv[7]);
            char* rp2 = Pout + ((size_t)i << 5);
            *(float4*)rp2        = make_float4(u01.f, u23.f, u45.f, u67.f);
            *(float2*)(rp2 + 16) = make_float2(hv[8], ad);
        }
    }
}

// ============ fused pool + fc ============

// One 64-thread block per graph. Two binary searches over sorted batch
// replace the gp[] array; 36 lanes pool their (layer,channel) column; 2
// lanes do the fc dot. m=0 init reproduces the isfinite->0 guard.
__global__ __launch_bounds__(64) void k_pool_fc(
    const float* __restrict__ jk, const int* __restrict__ batch,
    const float* __restrict__ fcw, const float* __restrict__ fcb,
    float* __restrict__ out)
{
    __shared__ float pl[JK];
    __shared__ int bounds[2];
    const int g = blockIdx.x;
    const int t = threadIdx.x;
    if (t < 2) {
        int target = g + t;
        int lo = 0, hi = Nn;
        while (lo < hi) {               // lower_bound(batch, target)
            int mid = (lo + hi) >> 1;
            if (batch[mid] < target) lo = mid + 1; else hi = mid;
        }
        bounds[t] = lo;
    }
    __syncthreads();
    const int beg = bounds[0], end = bounds[1];
    if (t < JK) {
        int lc = t / Hh, cc = t - lc * Hh;
        const float* bp = jk + (size_t)lc * Nn * Hh + cc;
        float m = 0.f;
        for (int i = beg; i < end; ++i)
            m = fmaxf(m, bp[(size_t)i * Hh]);
        pl[t] = m;
    }
    __syncthreads();
    if (t < Cc) {
        float s = fcb[t];
#pragma unroll
        for (int j = 0; j < JK; ++j) s += pl[j] * fcw[j * Cc + t];
        out[g * Cc + t] = s;
    }
}

extern "C" void kernel_launch(void* const* d_in, const int* in_sizes, int n_in,
                              void* d_out, int out_size, void* d_ws, size_t ws_size,
                              hipStream_t stream) {
    const float* x      = (const float*)d_in[0];   // [N,9]
    const int*   ei     = (const int*)d_in[1];     // [2,E]
    const int*   batch  = (const int*)d_in[2];     // [N] sorted
    const float* W      = (const float*)d_in[3];   // [L,9,9]
    const float* a_src  = (const float*)d_in[4];   // [L,9]
    const float* a_dst  = (const float*)d_in[5];   // [L,9]
    const float* bias   = (const float*)d_in[6];   // [L,9]
    const float* fc_w   = (const float*)d_in[7];   // [36,2]
    const float* fc_b   = (const float*)d_in[8];   // [2]
    float* out = (float*)d_out;

    // Workspace (~71 MB). bucketed aliases jk[0..26.4MB); histT lives in
    // jk's TAIL (jk+26.4MB, 635KB of the 2.4MB slack — dead before layer-3
    // agg writes that region; R12: P0 no longer aliases histT so the fused
    // transform can write P0 while kA writes histT).
    char* P0         = (char*)d_ws;                       // Nn*32B (6.4MB)
    char* P1         = P0 + ((size_t)Nn << 5);            // Nn*32B (6.4MB)
    float* jk        = (float*)(P1 + ((size_t)Nn << 5));  // Nn*JK (28.8MB)
    int* row_ptr     = (int*)(jk + (size_t)Nn * JK);      // Nn+1
    int* ctot        = row_ptr + Nn + 1;                  // NCB
    int* csr_src     = ctot + NCB;                        // EP (26.4MB)
    unsigned* bucketed = (unsigned*)jk;                   // jk[0..EP) alias
    int* histT       = (int*)((char*)jk + (size_t)EP * 4); // jk tail alias

    const int* srcp = ei;
    const int* dstp = ei + Ee;

    // CSR build + fused layer-0 transform (independent work, one dispatch)
    hipMemsetAsync(ctot, 0, NCB * sizeof(int), stream);
    kA_scatter<<<NBLKA + NB, 256, 0, stream>>>(srcp, dstp, ctot, histT,
                                               bucketed, x, W, a_dst, P0);
    kB_csr    <<<NCB, 1024, 0, stream>>>(bucketed, histT, ctot, row_ptr,
                                         csr_src);

    // Layers: records ping-pong P0/P1; layers 1..3 produced by agg epilogue.
    char* Pin = P0;
    char* Pout = P1;
    for (int l = 0; l < Ll; ++l) {
        const bool last = (l == Ll - 1);
        k_node_agg<<<NAB, 256, 0, stream>>>(
            row_ptr, csr_src, Pin, a_src + l * Hh, bias + l * Hh, jk, l,
            last ? nullptr : (W + (l + 1) * Hh * Hh),
            last ? nullptr : (a_dst + (l + 1) * Hh),
            last ? nullptr : Pout);
        char* tmp = Pin; Pin = Pout; Pout = tmp;
    }
    k_pool_fc<<<Gg, 64, 0, stream>>>(jk, batch, fc_w, fc_b, out);
}